// Round 6
// baseline (383.329 us; speedup 1.0000x reference)
//
#include <hip/hip_runtime.h>

#define N_ 256
#define L_ 4096
#define DM_ 2048
#define STEPF (1.0f / 4096.0f)
#define NW 22   // W-side Taylor terms: ||0.984*A||~2.2 -> 2.2^22/22! ~ 3e-14
#define NV 6    // V-side Taylor terms: ||63*step*A||~0.034 -> 0.034^6/6! ~ 2e-12
#define RQN 4608

typedef short bf16x8 __attribute__((ext_vector_type(8)));
typedef float f32x4 __attribute__((ext_vector_type(4)));
typedef unsigned int uint32;

__device__ __forceinline__ uint32 bf16rne(float f) {
    uint32 u = __builtin_bit_cast(uint32, f);
    return (u + 0x7FFFu + ((u >> 16) & 1u)) >> 16;
}
__device__ __forceinline__ uint32 pk2(float lo, float hi) {  // truncate-pack 2 f32 -> 2 bf16
    return (__builtin_bit_cast(uint32, hi) & 0xFFFF0000u) | (__builtin_bit_cast(uint32, lo) >> 16);
}
__device__ __forceinline__ float rdlane(float v, int l) {
    return __builtin_bit_cast(float, __builtin_amdgcn_readlane(__builtin_bit_cast(int, v), l));
}

// ---------------- Phase 1a: Krylov build of W (64x256) and V (256x64) ----------------
// S := ln(Abar) = step*A + O(M^3).  W[q,:] = C exp(64q S) = sum_n vt_n (q/63)^n,
// vt_n = C (4032 S)^n/n!.  V[:,r] = exp(r S) Bbar = sum_n ut_n (r/63)^n.
__global__ __launch_bounds__(1024) void k_kry(const float* __restrict__ Araw,
                                              const float* __restrict__ Bv,
                                              const float* __restrict__ Cv,
                                              float* __restrict__ W,
                                              float* __restrict__ V) {
    __shared__ float kry[NW][256];
    __shared__ float red[4][256];
    __shared__ float cur[256];
    const int tid = threadIdx.x;
    const int j = tid & 255, seg = tid >> 8, lane = tid & 63;

#define DOT64(S0, S1, VV) { \
    _Pragma("unroll") \
    for (int m = 0; m < 64; m += 2) { \
        S0 = fmaf(rdlane(VV, m), a[m], S0); \
        S1 = fmaf(rdlane(VV, m + 1), a[m + 1], S1); \
    } }

    if (blockIdx.x == 0) {
        float a[64];
#pragma unroll
        for (int m = 0; m < 64; ++m) a[m] = Araw[(64 * seg + m) * 256 + j];  // A[k][j]
        if (tid < 256) kry[0][tid] = Cv[tid];
        __syncthreads();
        const float WSC = 4032.0f / 4096.0f;
        for (int n = 1; n < NW; ++n) {
            float vv = kry[n - 1][64 * seg + lane];
            float s0 = 0.f, s1 = 0.f;
            DOT64(s0, s1, vv)
            red[seg][j] = s0 + s1;
            __syncthreads();
            if (tid < 256)
                kry[n][tid] = (red[0][tid] + red[1][tid] + red[2][tid] + red[3][tid]) * (WSC / (float)n);
            __syncthreads();
        }
        float kj[NW];
#pragma unroll
        for (int n = 0; n < NW; ++n) kj[n] = kry[n][j];
        for (int u = 0; u < 16; ++u) {
            int q = seg + 4 * u;
            float c = (float)q * (1.0f / 63.0f);
            float h = kj[NW - 1];
#pragma unroll
            for (int n = NW - 2; n >= 0; --n) h = fmaf(c, h, kj[n]);
            W[q * 256 + j] = h;
        }
    } else {
        float a[64];
#pragma unroll
        for (int m = 0; m < 64; ++m) a[m] = Araw[j * 256 + 64 * seg + m];  // A[i][k]
        if (tid < 256) cur[tid] = Bv[tid];
        __syncthreads();
        const float ms = 0.5f * STEPF;
        for (int it = 0; it < 3; ++it) {
            float vv = cur[64 * seg + lane];
            float s0 = 0.f, s1 = 0.f;
            DOT64(s0, s1, vv)
            red[seg][j] = s0 + s1;
            __syncthreads();
            if (tid < 256)
                cur[tid] = fmaf(ms, red[0][tid] + red[1][tid] + red[2][tid] + red[3][tid], Bv[tid]);
            __syncthreads();
        }
        if (tid < 256) kry[0][tid] = STEPF * cur[tid];
        __syncthreads();
        const float VSC = 63.0f / 4096.0f;
        for (int n = 1; n < NV; ++n) {
            float vv = kry[n - 1][64 * seg + lane];
            float s0 = 0.f, s1 = 0.f;
            DOT64(s0, s1, vv)
            red[seg][j] = s0 + s1;
            __syncthreads();
            if (tid < 256)
                kry[n][tid] = (red[0][tid] + red[1][tid] + red[2][tid] + red[3][tid]) * (VSC / (float)n);
            __syncthreads();
        }
        float kj[NV];
#pragma unroll
        for (int n = 0; n < NV; ++n) kj[n] = kry[n][j];
        for (int u = 0; u < 16; ++u) {
            int r = seg + 4 * u;
            float c = (float)r * (1.0f / 63.0f);
            float h = kj[NV - 1];
#pragma unroll
            for (int n = NV - 2; n >= 0; --n) h = fmaf(c, h, kj[n]);
            V[j * 64 + r] = h;
        }
    }
#undef DOT64
}

// ---------------- Phase 1b: small GEMM Kf = W * V  (Kf[64q + r] = K[l]) ----------------
__global__ __launch_bounds__(256) void k_g(const float* __restrict__ A, const float* __restrict__ B,
                                           float* __restrict__ C, int Ma, int Nb,
                                           int lda, int ldb, int ldc, float alpha, float diagv) {
    int row0 = blockIdx.y * 32, col0 = blockIdx.x * 32;
    if (row0 >= Ma || col0 >= Nb) return;
    __shared__ float As[16][33], Bs[16][33];
    int tid = threadIdx.x;
    int tx = tid & 15, ty = tid >> 4;
    int e0 = tid * 2, e1 = e0 + 1;
    int ai0 = e0 >> 4, ak0 = e0 & 15, ai1 = e1 >> 4, ak1 = e1 & 15;
    int bj0 = e0 & 31, bk0 = e0 >> 5, bj1 = e1 & 31, bk1 = e1 >> 5;
    bool va0 = (row0 + ai0) < Ma, va1 = (row0 + ai1) < Ma;
    bool vb0 = (col0 + bj0) < Nb, vb1 = (col0 + bj1) < Nb;
    float a0p = va0 ? A[(row0 + ai0) * lda + ak0] : 0.f;
    float a1p = va1 ? A[(row0 + ai1) * lda + ak1] : 0.f;
    float b0p = vb0 ? B[bk0 * ldb + col0 + bj0] : 0.f;
    float b1p = vb1 ? B[bk1 * ldb + col0 + bj1] : 0.f;
    float acc00 = 0.f, acc01 = 0.f, acc10 = 0.f, acc11 = 0.f;
    for (int kk = 0; kk < 256; kk += 16) {
        As[ak0][ai0] = a0p; As[ak1][ai1] = a1p;
        Bs[bk0][bj0] = b0p; Bs[bk1][bj1] = b1p;
        __syncthreads();
        if (kk + 16 < 256) {
            a0p = va0 ? A[(row0 + ai0) * lda + kk + 16 + ak0] : 0.f;
            a1p = va1 ? A[(row0 + ai1) * lda + kk + 16 + ak1] : 0.f;
            b0p = vb0 ? B[(bk0 + kk + 16) * ldb + col0 + bj0] : 0.f;
            b1p = vb1 ? B[(bk1 + kk + 16) * ldb + col0 + bj1] : 0.f;
        }
#pragma unroll
        for (int k = 0; k < 16; ++k) {
            float a0 = As[k][ty * 2], a1 = As[k][ty * 2 + 1];
            float b0 = Bs[k][tx * 2], b1 = Bs[k][tx * 2 + 1];
            acc00 = fmaf(a0, b0, acc00); acc01 = fmaf(a0, b1, acc01);
            acc10 = fmaf(a1, b0, acc10); acc11 = fmaf(a1, b1, acc11);
        }
        __syncthreads();
    }
    float accs[2][2] = {{acc00, acc01}, {acc10, acc11}};
#pragma unroll
    for (int i = 0; i < 2; ++i) {
        int r = row0 + ty * 2 + i;
        if (r < Ma)
#pragma unroll
            for (int jj = 0; jj < 2; ++jj) {
                int c = col0 + tx * 2 + jj;
                if (c < Nb) {
                    float v = alpha * accs[i][jj];
                    if (r == c) v += diagv;
                    C[r * ldc + c] = v;
                }
            }
    }
}

// ---------------- Phase 1c: pack reversed-K quad table to global ----------------
// Rqg[i] = rev[i..i+3] as 4 bf16 (uint2), rev[x] = K[4095-x], 0 when OOB.
__global__ __launch_bounds__(256) void k_pack(const float* __restrict__ Kf, uint2* __restrict__ Rqg) {
    int i = blockIdx.x * 256 + threadIdx.x;   // grid 18*256 = 4608
    int a = 4095 - i;
    uint32 e0 = (a >= 0) ? bf16rne(Kf[a]) : 0u;
    uint32 e1 = (a >= 1) ? bf16rne(Kf[a - 1]) : 0u;
    uint32 e2 = (a >= 2) ? bf16rne(Kf[a - 2]) : 0u;
    uint32 e3 = (a >= 3) ? bf16rne(Kf[a - 3]) : 0u;
    uint2 v; v.x = e0 | (e1 << 16); v.y = e2 | (e3 << 16);
    Rqg[i] = v;
}

// ---------------- Phase 2: MFMA causal conv, T=16, 2-way j-split ----------------
// Out[d,t] = sum_j y[d,j] K[t-j].  Block: 4 waves = (dsub 2) x (jhalf 2), 32 d-rows,
// 256 t.  Each wave: T=16 t-tiles, steps [jh*Sa, jh*Sa+Sa) of j-chunks of 32.
// Branch-free main loop (exact static waitcnts), period-8 slot rotation, y prefetch
// depth 2 with clamped indices, LDS reduction merges j-halves at the end.
__global__ __launch_bounds__(256, 3) void k_conv(const uint2* __restrict__ Rqg,
                                                 const float* __restrict__ y,
                                                 const float* __restrict__ Dp,
                                                 float* __restrict__ out) {
    __shared__ uint2 Rq[RQN];
    __shared__ f32x4 red[2][64][4];
    const int tid = threadIdx.x;
#pragma unroll
    for (int i = 0; i < RQN / 256; ++i) Rq[i * 256 + tid] = Rqg[i * 256 + tid];
    __syncthreads();

    const int w = tid >> 6, lane = tid & 63;
    const int n = lane & 15, g = lane >> 4;
    const int dsub = w & 1, jh = w >> 1;
    const int by = blockIdx.y;
    const int v = (by < 8) ? (15 - 2 * by) : (2 * (by - 8));  // pairs (by,by+8) sum const
    const int t0 = v * 256;
    const int d0w = (int)blockIdx.x * 32 + dsub * 16;
    const int d = d0w + n;
    const int S = (t0 >> 5) + 8;          // total j-steps for this t-block
    const int Sa = S >> 1;                // per-wave steps (multiple of 4)
    const int s0 = jh ? Sa : 0;
    const int nk = Sa;
    const float4* __restrict__ yq = (const float4*)(y + (size_t)d * L_);

    f32x4 acc[16];
#pragma unroll
    for (int i = 0; i < 16; ++i) acc[i] = (f32x4){0.f, 0.f, 0.f, 0.f};
    bf16x8 fr[16], av;
    uint2 pa0, pa1, pb0, pb1;
    float4 q0a, q0b, q1a, q1b;

#define LOADF(SL, I0) { \
    uint2 u0 = Rq[(I0)]; uint2 u1 = Rq[(I0) + 4]; \
    uint4 uu; uu.x = u0.x; uu.y = u0.y; uu.z = u1.x; uu.w = u1.y; \
    fr[SL] = __builtin_bit_cast(bf16x8, uu); }
#define PACKAV(Q0, Q1) { \
    uint4 ua; ua.x = pk2((Q0).x, (Q0).y); ua.y = pk2((Q0).z, (Q0).w); \
    ua.z = pk2((Q1).x, (Q1).y); ua.w = pk2((Q1).z, (Q1).w); \
    av = __builtin_bit_cast(bf16x8, ua); }
#define MF(TI, SL) acc[TI] = __builtin_amdgcn_mfma_f32_16x16x32_bf16(av, fr[SL], acc[TI], 0, 0, 0);
#define MFALL(S0,S1,S2,S3,S4,S5,S6,S7,S8,S9,S10,S11,S12,S13,S14,S15) \
    MF(0,S0) MF(1,S1) MF(2,S2) MF(3,S3) MF(4,S4) MF(5,S5) MF(6,S6) MF(7,S7) \
    MF(8,S8) MF(9,S9) MF(10,S10) MF(11,S11) MF(12,S12) MF(13,S13) MF(14,S14) MF(15,S15)

    const int B0 = 4095 - t0 - n + 8 * g + 32 * s0;
    // prefill slots 2..15 with frag(ti, s0); slots 0,1 arrive via pa/pb at k=0
#pragma unroll
    for (int ti = 2; ti < 16; ++ti) LOADF(ti, B0 - 16 * ti)
    pa0 = Rq[B0];      pa1 = Rq[B0 + 4];
    pb0 = Rq[B0 - 16]; pb1 = Rq[B0 - 12];
    {
        int i0 = 8 * s0 + 2 * g;
        q0a = yq[i0];     q0b = yq[i0 + 1];
        q1a = yq[i0 + 8]; q1b = yq[i0 + 9];
    }
    int bcur = B0 - 32;
    int yn = 8 * s0 + 16 + 2 * g;   // float4 index for y prefetch (k+2 ahead)

#define STEPP(S0,S1,S2,S3,S4,S5,S6,S7,S8,S9,S10,S11,S12,S13,S14,S15) { \
    { uint4 u; u.x = pa0.x; u.y = pa0.y; u.z = pa1.x; u.w = pa1.y; fr[S0] = __builtin_bit_cast(bf16x8, u); } \
    { uint4 u; u.x = pb0.x; u.y = pb0.y; u.z = pb1.x; u.w = pb1.y; fr[S1] = __builtin_bit_cast(bf16x8, u); } \
    PACKAV(q0a, q0b); \
    q0a = q1a; q0b = q1b; \
    { int yi = (yn < 1016) ? yn : 1016; q1a = yq[yi]; q1b = yq[yi + 1]; yn += 8; } \
    bcur += 32; \
    pa0 = Rq[bcur + 32]; pa1 = Rq[bcur + 36]; \
    pb0 = Rq[bcur + 16]; pb1 = Rq[bcur + 20]; \
    __builtin_amdgcn_s_setprio(1); \
    MFALL(S0,S1,S2,S3,S4,S5,S6,S7,S8,S9,S10,S11,S12,S13,S14,S15) \
    __builtin_amdgcn_s_setprio(0); \
}

    const int nfull = nk >> 3;
    for (int it = 0; it < nfull; ++it) {
        STEPP(0,1,2,3,4,5,6,7,8,9,10,11,12,13,14,15)
        STEPP(14,15,0,1,2,3,4,5,6,7,8,9,10,11,12,13)
        STEPP(12,13,14,15,0,1,2,3,4,5,6,7,8,9,10,11)
        STEPP(10,11,12,13,14,15,0,1,2,3,4,5,6,7,8,9)
        STEPP(8,9,10,11,12,13,14,15,0,1,2,3,4,5,6,7)
        STEPP(6,7,8,9,10,11,12,13,14,15,0,1,2,3,4,5)
        STEPP(4,5,6,7,8,9,10,11,12,13,14,15,0,1,2,3)
        STEPP(2,3,4,5,6,7,8,9,10,11,12,13,14,15,0,1)
    }
    if (nk & 4) {
        STEPP(0,1,2,3,4,5,6,7,8,9,10,11,12,13,14,15)
        STEPP(14,15,0,1,2,3,4,5,6,7,8,9,10,11,12,13)
        STEPP(12,13,14,15,0,1,2,3,4,5,6,7,8,9,10,11)
        STEPP(10,11,12,13,14,15,0,1,2,3,4,5,6,7,8,9)
    }
#undef STEPP
#undef MFALL
#undef MF
#undef PACKAV
#undef LOADF

    // ---- merge j-halves: jh1 writes, jh0 adds (4 rounds of acc[4]) ----
#pragma unroll
    for (int cc = 0; cc < 4; ++cc) {
        if (jh == 1) {
#pragma unroll
            for (int i = 0; i < 4; ++i) red[dsub][lane][i] = acc[4 * cc + i];
        }
        __syncthreads();
        if (jh == 0) {
#pragma unroll
            for (int i = 0; i < 4; ++i) acc[4 * cc + i] += red[dsub][lane][i];
        }
        __syncthreads();
    }

    // ---- epilogue: out = acc + D*y (jh0 waves) ----
    if (jh == 0) {
        const float D0 = Dp[0];
#pragma unroll
        for (int ti = 0; ti < 16; ++ti) {
            int tcol = t0 + 16 * ti + n;
#pragma unroll
            for (int r = 0; r < 4; ++r) {
                int dr = d0w + 4 * g + r;
                size_t ix = (size_t)dr * L_ + tcol;
                out[ix] = acc[ti][r] + D0 * y[ix];
            }
        }
    }
}

// ---------------- host ----------------

extern "C" void kernel_launch(void* const* d_in, const int* in_sizes, int n_in,
                              void* d_out, int out_size, void* d_ws, size_t ws_size,
                              hipStream_t stream) {
    const float* y  = (const float*)d_in[0];
    const float* A  = (const float*)d_in[1];
    const float* Bv = (const float*)d_in[2];
    const float* Cv = (const float*)d_in[3];
    const float* Dp = (const float*)d_in[4];
    float* out = (float*)d_out;
    float* w = (float*)d_ws;

    float* W   = w;                    // 64 x 256
    float* V   = w + 16384;            // 256 x 64
    float* Kf  = w + 32768;            // 4096
    uint2* Rqg = (uint2*)(w + 36864);  // 4608 quads (36,864 B)

    k_kry<<<dim3(2), dim3(1024), 0, stream>>>(A, Bv, Cv, W, V);
    k_g<<<dim3(2, 2), dim3(256), 0, stream>>>(W, V, Kf, 64, 64, 256, 64, 64, 1.0f, 0.0f);
    k_pack<<<dim3(18), dim3(256), 0, stream>>>(Kf, Rqg);
    k_conv<<<dim3(64, 16), dim3(256), 0, stream>>>(Rqg, y, Dp, out);

    (void)in_sizes; (void)n_in; (void)out_size; (void)ws_size;
}

// Round 7
// 91.429 us; speedup vs baseline: 4.1926x; 4.1926x over previous
//
#include <hip/hip_runtime.h>

#define N_ 256
#define L_ 4096
#define DM_ 2048
#define STEPF (1.0f / 4096.0f)
#define NW 22   // W-side Taylor terms: ||0.984*A||~2.2 -> 2.2^22/22! ~ 3e-14
#define NV 6    // V-side Taylor terms: ||63*step*A||~0.034 -> 0.034^6/6! ~ 2e-12
#define RQN 4608

typedef short bf16x8 __attribute__((ext_vector_type(8)));
typedef float f32x4 __attribute__((ext_vector_type(4)));
typedef unsigned int uint32;

__device__ __forceinline__ uint32 bf16rne(float f) {
    uint32 u = __builtin_bit_cast(uint32, f);
    return (u + 0x7FFFu + ((u >> 16) & 1u)) >> 16;
}
__device__ __forceinline__ uint32 pk2(float lo, float hi) {  // truncate-pack 2 f32 -> 2 bf16
    return (__builtin_bit_cast(uint32, hi) & 0xFFFF0000u) | (__builtin_bit_cast(uint32, lo) >> 16);
}
__device__ __forceinline__ float rdlane(float v, int l) {
    return __builtin_bit_cast(float, __builtin_amdgcn_readlane(__builtin_bit_cast(int, v), l));
}

// ---------------- Phase 1a: Krylov build of W (64x256) and V (256x64) ----------------
// S := ln(Abar) = step*A + O(M^3).  W[q,:] = C exp(64q S) = sum_n vt_n (q/63)^n,
// vt_n = C (4032 S)^n/n!.  V[:,r] = exp(r S) Bbar = sum_n ut_n (r/63)^n.
__global__ __launch_bounds__(1024) void k_kry(const float* __restrict__ Araw,
                                              const float* __restrict__ Bv,
                                              const float* __restrict__ Cv,
                                              float* __restrict__ W,
                                              float* __restrict__ V) {
    __shared__ float kry[NW][256];
    __shared__ float red[4][256];
    __shared__ float cur[256];
    const int tid = threadIdx.x;
    const int j = tid & 255, seg = tid >> 8, lane = tid & 63;

#define DOT64(S0, S1, VV) { \
    _Pragma("unroll") \
    for (int m = 0; m < 64; m += 2) { \
        S0 = fmaf(rdlane(VV, m), a[m], S0); \
        S1 = fmaf(rdlane(VV, m + 1), a[m + 1], S1); \
    } }

    if (blockIdx.x == 0) {
        float a[64];
#pragma unroll
        for (int m = 0; m < 64; ++m) a[m] = Araw[(64 * seg + m) * 256 + j];  // A[k][j]
        if (tid < 256) kry[0][tid] = Cv[tid];
        __syncthreads();
        const float WSC = 4032.0f / 4096.0f;
        for (int n = 1; n < NW; ++n) {
            float vv = kry[n - 1][64 * seg + lane];
            float s0 = 0.f, s1 = 0.f;
            DOT64(s0, s1, vv)
            red[seg][j] = s0 + s1;
            __syncthreads();
            if (tid < 256)
                kry[n][tid] = (red[0][tid] + red[1][tid] + red[2][tid] + red[3][tid]) * (WSC / (float)n);
            __syncthreads();
        }
        float kj[NW];
#pragma unroll
        for (int n = 0; n < NW; ++n) kj[n] = kry[n][j];
        for (int u = 0; u < 16; ++u) {
            int q = seg + 4 * u;
            float c = (float)q * (1.0f / 63.0f);
            float h = kj[NW - 1];
#pragma unroll
            for (int n = NW - 2; n >= 0; --n) h = fmaf(c, h, kj[n]);
            W[q * 256 + j] = h;
        }
    } else {
        float a[64];
#pragma unroll
        for (int m = 0; m < 64; ++m) a[m] = Araw[j * 256 + 64 * seg + m];  // A[i][k]
        if (tid < 256) cur[tid] = Bv[tid];
        __syncthreads();
        const float ms = 0.5f * STEPF;
        for (int it = 0; it < 3; ++it) {
            float vv = cur[64 * seg + lane];
            float s0 = 0.f, s1 = 0.f;
            DOT64(s0, s1, vv)
            red[seg][j] = s0 + s1;
            __syncthreads();
            if (tid < 256)
                cur[tid] = fmaf(ms, red[0][tid] + red[1][tid] + red[2][tid] + red[3][tid], Bv[tid]);
            __syncthreads();
        }
        if (tid < 256) kry[0][tid] = STEPF * cur[tid];
        __syncthreads();
        const float VSC = 63.0f / 4096.0f;
        for (int n = 1; n < NV; ++n) {
            float vv = kry[n - 1][64 * seg + lane];
            float s0 = 0.f, s1 = 0.f;
            DOT64(s0, s1, vv)
            red[seg][j] = s0 + s1;
            __syncthreads();
            if (tid < 256)
                kry[n][tid] = (red[0][tid] + red[1][tid] + red[2][tid] + red[3][tid]) * (VSC / (float)n);
            __syncthreads();
        }
        float kj[NV];
#pragma unroll
        for (int n = 0; n < NV; ++n) kj[n] = kry[n][j];
        for (int u = 0; u < 16; ++u) {
            int r = seg + 4 * u;
            float c = (float)r * (1.0f / 63.0f);
            float h = kj[NV - 1];
#pragma unroll
            for (int n = NV - 2; n >= 0; --n) h = fmaf(c, h, kj[n]);
            V[j * 64 + r] = h;
        }
    }
#undef DOT64
}

// ---------------- Phase 1b: small GEMM Kf = W * V  (Kf[64q + r] = K[l]) ----------------
__global__ __launch_bounds__(256) void k_g(const float* __restrict__ A, const float* __restrict__ B,
                                           float* __restrict__ C, int Ma, int Nb,
                                           int lda, int ldb, int ldc, float alpha, float diagv) {
    int row0 = blockIdx.y * 32, col0 = blockIdx.x * 32;
    if (row0 >= Ma || col0 >= Nb) return;
    __shared__ float As[16][33], Bs[16][33];
    int tid = threadIdx.x;
    int tx = tid & 15, ty = tid >> 4;
    int e0 = tid * 2, e1 = e0 + 1;
    int ai0 = e0 >> 4, ak0 = e0 & 15, ai1 = e1 >> 4, ak1 = e1 & 15;
    int bj0 = e0 & 31, bk0 = e0 >> 5, bj1 = e1 & 31, bk1 = e1 >> 5;
    bool va0 = (row0 + ai0) < Ma, va1 = (row0 + ai1) < Ma;
    bool vb0 = (col0 + bj0) < Nb, vb1 = (col0 + bj1) < Nb;
    float a0p = va0 ? A[(row0 + ai0) * lda + ak0] : 0.f;
    float a1p = va1 ? A[(row0 + ai1) * lda + ak1] : 0.f;
    float b0p = vb0 ? B[bk0 * ldb + col0 + bj0] : 0.f;
    float b1p = vb1 ? B[bk1 * ldb + col0 + bj1] : 0.f;
    float acc00 = 0.f, acc01 = 0.f, acc10 = 0.f, acc11 = 0.f;
    for (int kk = 0; kk < 256; kk += 16) {
        As[ak0][ai0] = a0p; As[ak1][ai1] = a1p;
        Bs[bk0][bj0] = b0p; Bs[bk1][bj1] = b1p;
        __syncthreads();
        if (kk + 16 < 256) {
            a0p = va0 ? A[(row0 + ai0) * lda + kk + 16 + ak0] : 0.f;
            a1p = va1 ? A[(row0 + ai1) * lda + kk + 16 + ak1] : 0.f;
            b0p = vb0 ? B[(bk0 + kk + 16) * ldb + col0 + bj0] : 0.f;
            b1p = vb1 ? B[(bk1 + kk + 16) * ldb + col0 + bj1] : 0.f;
        }
#pragma unroll
        for (int k = 0; k < 16; ++k) {
            float a0 = As[k][ty * 2], a1 = As[k][ty * 2 + 1];
            float b0 = Bs[k][tx * 2], b1 = Bs[k][tx * 2 + 1];
            acc00 = fmaf(a0, b0, acc00); acc01 = fmaf(a0, b1, acc01);
            acc10 = fmaf(a1, b0, acc10); acc11 = fmaf(a1, b1, acc11);
        }
        __syncthreads();
    }
    float accs[2][2] = {{acc00, acc01}, {acc10, acc11}};
#pragma unroll
    for (int i = 0; i < 2; ++i) {
        int r = row0 + ty * 2 + i;
        if (r < Ma)
#pragma unroll
            for (int jj = 0; jj < 2; ++jj) {
                int c = col0 + tx * 2 + jj;
                if (c < Nb) {
                    float v = alpha * accs[i][jj];
                    if (r == c) v += diagv;
                    C[r * ldc + c] = v;
                }
            }
    }
}

// ---------------- Phase 1c: pack reversed-K quad table to global ----------------
// Rqg[i] = rev[i..i+3] as 4 bf16 (uint2), rev[x] = K[4095-x], 0 when OOB.
__global__ __launch_bounds__(256) void k_pack(const float* __restrict__ Kf, uint2* __restrict__ Rqg) {
    int i = blockIdx.x * 256 + threadIdx.x;   // grid 18*256 = 4608
    int a = 4095 - i;
    uint32 e0 = (a >= 0) ? bf16rne(Kf[a]) : 0u;
    uint32 e1 = (a >= 1) ? bf16rne(Kf[a - 1]) : 0u;
    uint32 e2 = (a >= 2) ? bf16rne(Kf[a - 2]) : 0u;
    uint32 e3 = (a >= 3) ? bf16rne(Kf[a - 3]) : 0u;
    uint2 v; v.x = e0 | (e1 << 16); v.y = e2 | (e3 << 16);
    Rqg[i] = v;
}

// ---------------- Phase 2: MFMA causal conv, T=16, branch-free main loop ----------------
// Out[d,t] = sum_j y[d,j] K[t-j].  4 waves = 4 d-subtiles (64 d-rows), 256 t per block.
// S = 8(v+1) steps, always divisible by 8 -> all steps run through the unguarded
// period-8 rotation (exact counted waitcnts, loads stay in flight across steps).
// Per step: 2 new K-frags (rotation frag(ti,s+1)==frag(ti-2,s)) + 1 y packet, 16 MFMAs.
__global__ __launch_bounds__(256, 2) void k_conv(const uint2* __restrict__ Rqg,
                                                 const float* __restrict__ y,
                                                 const float* __restrict__ Dp,
                                                 float* __restrict__ out) {
    __shared__ uint2 Rq[RQN];
    const int tid = threadIdx.x;
#pragma unroll
    for (int i = 0; i < RQN / 256; ++i) Rq[i * 256 + tid] = Rqg[i * 256 + tid];
    __syncthreads();

    const int w = tid >> 6, lane = tid & 63;
    const int n = lane & 15, g = lane >> 4;
    const int v = 15 - (int)blockIdx.y;               // heavy t-blocks dispatched first
    const int t0 = v * 256;
    const int d0w = (int)blockIdx.x * 64 + w * 16;
    const int d = d0w + n;
    const int S = 8 * (v + 1);                        // j-steps (chunks of 32)
    const float4* __restrict__ yq = (const float4*)(y + (size_t)d * L_);

    f32x4 acc[16];
#pragma unroll
    for (int i = 0; i < 16; ++i) acc[i] = (f32x4){0.f, 0.f, 0.f, 0.f};
    bf16x8 fr[16], av;
    uint2 pa0, pa1, pb0, pb1;
    float4 q0a, q0b, q1a, q1b;

#define LOADF(SL, I0) { \
    uint2 u0 = Rq[(I0)]; uint2 u1 = Rq[(I0) + 4]; \
    uint4 uu; uu.x = u0.x; uu.y = u0.y; uu.z = u1.x; uu.w = u1.y; \
    fr[SL] = __builtin_bit_cast(bf16x8, uu); }
#define PACKAV(Q0, Q1) { \
    uint4 ua; ua.x = pk2((Q0).x, (Q0).y); ua.y = pk2((Q0).z, (Q0).w); \
    ua.z = pk2((Q1).x, (Q1).y); ua.w = pk2((Q1).z, (Q1).w); \
    av = __builtin_bit_cast(bf16x8, ua); }
#define MF(TI, SL) acc[TI] = __builtin_amdgcn_mfma_f32_16x16x32_bf16(av, fr[SL], acc[TI], 0, 0, 0);
#define MFALL(S0,S1,S2,S3,S4,S5,S6,S7,S8,S9,S10,S11,S12,S13,S14,S15) \
    MF(0,S0) MF(1,S1) MF(2,S2) MF(3,S3) MF(4,S4) MF(5,S5) MF(6,S6) MF(7,S7) \
    MF(8,S8) MF(9,S9) MF(10,S10) MF(11,S11) MF(12,S12) MF(13,S13) MF(14,S14) MF(15,S15)

    const int B0 = 4095 - t0 - n + 8 * g;
    // prefill slots 2..15 with frag(ti,0); slots 0,1 arrive via pa/pb at step 0
#pragma unroll
    for (int ti = 2; ti < 16; ++ti) LOADF(ti, B0 - 16 * ti)
    pa0 = Rq[B0];      pa1 = Rq[B0 + 4];
    pb0 = Rq[B0 - 16]; pb1 = Rq[B0 - 12];
    q0a = yq[2 * g];     q0b = yq[2 * g + 1];
    q1a = yq[8 + 2 * g]; q1b = yq[8 + 2 * g + 1];
    int bcur = B0 - 32;
    int yn = 16 + 2 * g;   // float4 index for y prefetch, 2 steps ahead

#define STEPP(S0,S1,S2,S3,S4,S5,S6,S7,S8,S9,S10,S11,S12,S13,S14,S15) { \
    { uint4 u; u.x = pa0.x; u.y = pa0.y; u.z = pa1.x; u.w = pa1.y; fr[S0] = __builtin_bit_cast(bf16x8, u); } \
    { uint4 u; u.x = pb0.x; u.y = pb0.y; u.z = pb1.x; u.w = pb1.y; fr[S1] = __builtin_bit_cast(bf16x8, u); } \
    PACKAV(q0a, q0b); \
    q0a = q1a; q0b = q1b; \
    { int yi = (yn < 1016) ? yn : 1016; q1a = yq[yi]; q1b = yq[yi + 1]; yn += 8; } \
    bcur += 32; \
    pa0 = Rq[bcur + 32]; pa1 = Rq[bcur + 36]; \
    pb0 = Rq[bcur + 16]; pb1 = Rq[bcur + 20]; \
    __builtin_amdgcn_s_setprio(1); \
    MFALL(S0,S1,S2,S3,S4,S5,S6,S7,S8,S9,S10,S11,S12,S13,S14,S15) \
    __builtin_amdgcn_s_setprio(0); \
}

    const int nfull = S >> 3;
    for (int it = 0; it < nfull; ++it) {
        STEPP(0,1,2,3,4,5,6,7,8,9,10,11,12,13,14,15)
        STEPP(14,15,0,1,2,3,4,5,6,7,8,9,10,11,12,13)
        STEPP(12,13,14,15,0,1,2,3,4,5,6,7,8,9,10,11)
        STEPP(10,11,12,13,14,15,0,1,2,3,4,5,6,7,8,9)
        STEPP(8,9,10,11,12,13,14,15,0,1,2,3,4,5,6,7)
        STEPP(6,7,8,9,10,11,12,13,14,15,0,1,2,3,4,5)
        STEPP(4,5,6,7,8,9,10,11,12,13,14,15,0,1,2,3)
        STEPP(2,3,4,5,6,7,8,9,10,11,12,13,14,15,0,1)
    }
#undef STEPP
#undef MFALL
#undef MF
#undef PACKAV
#undef LOADF

    // ---- epilogue: out = acc + D*y ----
    const float D0 = Dp[0];
#pragma unroll
    for (int ti = 0; ti < 16; ++ti) {
        int tcol = t0 + 16 * ti + n;
#pragma unroll
        for (int r = 0; r < 4; ++r) {
            int dr = d0w + 4 * g + r;
            size_t ix = (size_t)dr * L_ + tcol;
            out[ix] = acc[ti][r] + D0 * y[ix];
        }
    }
}

// ---------------- host ----------------

extern "C" void kernel_launch(void* const* d_in, const int* in_sizes, int n_in,
                              void* d_out, int out_size, void* d_ws, size_t ws_size,
                              hipStream_t stream) {
    const float* y  = (const float*)d_in[0];
    const float* A  = (const float*)d_in[1];
    const float* Bv = (const float*)d_in[2];
    const float* Cv = (const float*)d_in[3];
    const float* Dp = (const float*)d_in[4];
    float* out = (float*)d_out;
    float* w = (float*)d_ws;

    float* W   = w;                    // 64 x 256
    float* V   = w + 16384;            // 256 x 64
    float* Kf  = w + 32768;            // 4096
    uint2* Rqg = (uint2*)(w + 36864);  // 4608 quads

    k_kry<<<dim3(2), dim3(1024), 0, stream>>>(A, Bv, Cv, W, V);
    k_g<<<dim3(2, 2), dim3(256), 0, stream>>>(W, V, Kf, 64, 64, 256, 64, 64, 1.0f, 0.0f);
    k_pack<<<dim3(18), dim3(256), 0, stream>>>(Kf, Rqg);
    k_conv<<<dim3(32, 16), dim3(256), 0, stream>>>(Rqg, y, Dp, out);

    (void)in_sizes; (void)n_in; (void)out_size; (void)ws_size;
}

// Round 8
// 80.155 us; speedup vs baseline: 4.7824x; 1.1407x over previous
//
#include <hip/hip_runtime.h>

#define N_ 256
#define L_ 4096
#define DM_ 2048
#define STEPF (1.0f / 4096.0f)
#define NW 22   // W-side Taylor terms: ||0.984*A||~2.2 -> 2.2^22/22! ~ 3e-14
#define NV 6    // V-side Taylor terms: ||63*step*A||~0.034 -> 0.034^6/6! ~ 2e-12
#define RQN 4608

typedef short bf16x8 __attribute__((ext_vector_type(8)));
typedef float f32x4 __attribute__((ext_vector_type(4)));
typedef unsigned int uint32;

__device__ __forceinline__ uint32 bf16rne(float f) {
    uint32 u = __builtin_bit_cast(uint32, f);
    return (u + 0x7FFFu + ((u >> 16) & 1u)) >> 16;
}
__device__ __forceinline__ float rdlane(float v, int l) {
    return __builtin_bit_cast(float, __builtin_amdgcn_readlane(__builtin_bit_cast(int, v), l));
}

// ---------------- Phase 1a: Krylov build of W (64x256) and V (256x64) ----------------
// S := ln(Abar) = step*A + O(M^3).  W[q,:] = C exp(64q S) = sum_n vt_n (q/63)^n,
// vt_n = C (4032 S)^n/n!.  V[:,r] = exp(r S) Bbar = sum_n ut_n (r/63)^n.
__global__ __launch_bounds__(1024) void k_kry(const float* __restrict__ Araw,
                                              const float* __restrict__ Bv,
                                              const float* __restrict__ Cv,
                                              float* __restrict__ W,
                                              float* __restrict__ V) {
    __shared__ float kry[NW][256];
    __shared__ float red[4][256];
    __shared__ float cur[256];
    const int tid = threadIdx.x;
    const int j = tid & 255, seg = tid >> 8, lane = tid & 63;

#define DOT64(S0, S1, VV) { \
    _Pragma("unroll") \
    for (int m = 0; m < 64; m += 2) { \
        S0 = fmaf(rdlane(VV, m), a[m], S0); \
        S1 = fmaf(rdlane(VV, m + 1), a[m + 1], S1); \
    } }

    if (blockIdx.x == 0) {
        float a[64];
#pragma unroll
        for (int m = 0; m < 64; ++m) a[m] = Araw[(64 * seg + m) * 256 + j];  // A[k][j]
        if (tid < 256) kry[0][tid] = Cv[tid];
        __syncthreads();
        const float WSC = 4032.0f / 4096.0f;
        for (int n = 1; n < NW; ++n) {
            float vv = kry[n - 1][64 * seg + lane];
            float s0 = 0.f, s1 = 0.f;
            DOT64(s0, s1, vv)
            red[seg][j] = s0 + s1;
            __syncthreads();
            if (tid < 256)
                kry[n][tid] = (red[0][tid] + red[1][tid] + red[2][tid] + red[3][tid]) * (WSC / (float)n);
            __syncthreads();
        }
        float kj[NW];
#pragma unroll
        for (int n = 0; n < NW; ++n) kj[n] = kry[n][j];
        for (int u = 0; u < 16; ++u) {
            int q = seg + 4 * u;
            float c = (float)q * (1.0f / 63.0f);
            float h = kj[NW - 1];
#pragma unroll
            for (int n = NW - 2; n >= 0; --n) h = fmaf(c, h, kj[n]);
            W[q * 256 + j] = h;
        }
    } else {
        float a[64];
#pragma unroll
        for (int m = 0; m < 64; ++m) a[m] = Araw[j * 256 + 64 * seg + m];  // A[i][k]
        if (tid < 256) cur[tid] = Bv[tid];
        __syncthreads();
        const float ms = 0.5f * STEPF;
        for (int it = 0; it < 3; ++it) {
            float vv = cur[64 * seg + lane];
            float s0 = 0.f, s1 = 0.f;
            DOT64(s0, s1, vv)
            red[seg][j] = s0 + s1;
            __syncthreads();
            if (tid < 256)
                cur[tid] = fmaf(ms, red[0][tid] + red[1][tid] + red[2][tid] + red[3][tid], Bv[tid]);
            __syncthreads();
        }
        if (tid < 256) kry[0][tid] = STEPF * cur[tid];
        __syncthreads();
        const float VSC = 63.0f / 4096.0f;
        for (int n = 1; n < NV; ++n) {
            float vv = kry[n - 1][64 * seg + lane];
            float s0 = 0.f, s1 = 0.f;
            DOT64(s0, s1, vv)
            red[seg][j] = s0 + s1;
            __syncthreads();
            if (tid < 256)
                kry[n][tid] = (red[0][tid] + red[1][tid] + red[2][tid] + red[3][tid]) * (VSC / (float)n);
            __syncthreads();
        }
        float kj[NV];
#pragma unroll
        for (int n = 0; n < NV; ++n) kj[n] = kry[n][j];
        for (int u = 0; u < 16; ++u) {
            int r = seg + 4 * u;
            float c = (float)r * (1.0f / 63.0f);
            float h = kj[NV - 1];
#pragma unroll
            for (int n = NV - 2; n >= 0; --n) h = fmaf(c, h, kj[n]);
            V[j * 64 + r] = h;
        }
    }
#undef DOT64
}

// ---------------- Phase 1b: small GEMM Kf = W * V  (Kf[64q + r] = K[l]) ----------------
__global__ __launch_bounds__(256) void k_g(const float* __restrict__ A, const float* __restrict__ B,
                                           float* __restrict__ C, int Ma, int Nb,
                                           int lda, int ldb, int ldc, float alpha, float diagv) {
    int row0 = blockIdx.y * 32, col0 = blockIdx.x * 32;
    if (row0 >= Ma || col0 >= Nb) return;
    __shared__ float As[16][33], Bs[16][33];
    int tid = threadIdx.x;
    int tx = tid & 15, ty = tid >> 4;
    int e0 = tid * 2, e1 = e0 + 1;
    int ai0 = e0 >> 4, ak0 = e0 & 15, ai1 = e1 >> 4, ak1 = e1 & 15;
    int bj0 = e0 & 31, bk0 = e0 >> 5, bj1 = e1 & 31, bk1 = e1 >> 5;
    bool va0 = (row0 + ai0) < Ma, va1 = (row0 + ai1) < Ma;
    bool vb0 = (col0 + bj0) < Nb, vb1 = (col0 + bj1) < Nb;
    float a0p = va0 ? A[(row0 + ai0) * lda + ak0] : 0.f;
    float a1p = va1 ? A[(row0 + ai1) * lda + ak1] : 0.f;
    float b0p = vb0 ? B[bk0 * ldb + col0 + bj0] : 0.f;
    float b1p = vb1 ? B[bk1 * ldb + col0 + bj1] : 0.f;
    float acc00 = 0.f, acc01 = 0.f, acc10 = 0.f, acc11 = 0.f;
    for (int kk = 0; kk < 256; kk += 16) {
        As[ak0][ai0] = a0p; As[ak1][ai1] = a1p;
        Bs[bk0][bj0] = b0p; Bs[bk1][bj1] = b1p;
        __syncthreads();
        if (kk + 16 < 256) {
            a0p = va0 ? A[(row0 + ai0) * lda + kk + 16 + ak0] : 0.f;
            a1p = va1 ? A[(row0 + ai1) * lda + kk + 16 + ak1] : 0.f;
            b0p = vb0 ? B[(bk0 + kk + 16) * ldb + col0 + bj0] : 0.f;
            b1p = vb1 ? B[(bk1 + kk + 16) * ldb + col0 + bj1] : 0.f;
        }
#pragma unroll
        for (int k = 0; k < 16; ++k) {
            float a0 = As[k][ty * 2], a1 = As[k][ty * 2 + 1];
            float b0 = Bs[k][tx * 2], b1 = Bs[k][tx * 2 + 1];
            acc00 = fmaf(a0, b0, acc00); acc01 = fmaf(a0, b1, acc01);
            acc10 = fmaf(a1, b0, acc10); acc11 = fmaf(a1, b1, acc11);
        }
        __syncthreads();
    }
    float accs[2][2] = {{acc00, acc01}, {acc10, acc11}};
#pragma unroll
    for (int i = 0; i < 2; ++i) {
        int r = row0 + ty * 2 + i;
        if (r < Ma)
#pragma unroll
            for (int jj = 0; jj < 2; ++jj) {
                int c = col0 + tx * 2 + jj;
                if (c < Nb) {
                    float v = alpha * accs[i][jj];
                    if (r == c) v += diagv;
                    C[r * ldc + c] = v;
                }
            }
    }
}

// ---------------- Phase 1c: pack reversed-K quad table to global ----------------
// Rqg[i] = rev[i..i+3] as 4 bf16 (uint2), rev[x] = K[4095-x], 0 when OOB.
__global__ __launch_bounds__(256) void k_pack(const float* __restrict__ Kf, uint2* __restrict__ Rqg) {
    int i = blockIdx.x * 256 + threadIdx.x;   // grid 18*256 = 4608
    int a = 4095 - i;
    uint32 e0 = (a >= 0) ? bf16rne(Kf[a]) : 0u;
    uint32 e1 = (a >= 1) ? bf16rne(Kf[a - 1]) : 0u;
    uint32 e2 = (a >= 2) ? bf16rne(Kf[a - 2]) : 0u;
    uint32 e3 = (a >= 3) ? bf16rne(Kf[a - 3]) : 0u;
    uint2 v; v.x = e0 | (e1 << 16); v.y = e2 | (e3 << 16);
    Rqg[i] = v;
}

// ---------------- Phase 2: MFMA causal conv, T=16, lean issue path ----------------
// Out[d,t] = sum_j y[d,j] K[t-j].  4 waves = 4 d-subtiles (64 d-rows), 256 t per block.
// Per step: 16 MFMAs, 2 new K-frags ds_read DIRECTLY into the slots just consumed
// (MF(14),MF(15) ordered first), y pack via single v_perm per pair. Main loop is
// branch/clamp-free (affine addresses fold to offsets); final 8-step iter peeled
// with clamped y prefetch.
__global__ __launch_bounds__(256, 2) void k_conv(const uint2* __restrict__ Rqg,
                                                 const float* __restrict__ y,
                                                 const float* __restrict__ Dp,
                                                 float* __restrict__ out) {
    __shared__ uint2 Rq[RQN];
    const int tid = threadIdx.x;
#pragma unroll
    for (int i = 0; i < RQN / 256; ++i) Rq[i * 256 + tid] = Rqg[i * 256 + tid];
    __syncthreads();

    const int w = tid >> 6, lane = tid & 63;
    const int n = lane & 15, g = lane >> 4;
    const int by = (int)blockIdx.y;
    const int v = (by < 8) ? (15 - 2 * by) : (2 * (by - 8));  // pairs (by, by+8) sum 15
    const int t0 = v * 256;
    const int d0w = (int)blockIdx.x * 64 + w * 16;
    const int d = d0w + n;
    const int S = 8 * (v + 1);                        // j-steps (chunks of 32)
    const float4* __restrict__ yq = (const float4*)(y + (size_t)d * L_);

    f32x4 acc[16];
#pragma unroll
    for (int i = 0; i < 16; ++i) acc[i] = (f32x4){0.f, 0.f, 0.f, 0.f};
    bf16x8 fr[16], av;
    float4 q0a, q0b, q1a, q1b;

#define LOADF(SL, I0) { \
    uint2 u0 = Rq[(I0)]; uint2 u1 = Rq[(I0) + 4]; \
    uint4 uu; uu.x = u0.x; uu.y = u0.y; uu.z = u1.x; uu.w = u1.y; \
    fr[SL] = __builtin_bit_cast(bf16x8, uu); }
// pk2 as one v_perm: result bytes = {hi.b3, hi.b2, lo.b3, lo.b2} (bf16 truncation)
#define PK2(LO, HI) __builtin_amdgcn_perm(__builtin_bit_cast(uint32, (HI)), \
                                          __builtin_bit_cast(uint32, (LO)), 0x07060302u)
#define PACKAV(Q0, Q1) { \
    uint4 ua; ua.x = PK2((Q0).x, (Q0).y); ua.y = PK2((Q0).z, (Q0).w); \
    ua.z = PK2((Q1).x, (Q1).y); ua.w = PK2((Q1).z, (Q1).w); \
    av = __builtin_bit_cast(bf16x8, ua); }
#define MF(TI, SL) acc[TI] = __builtin_amdgcn_mfma_f32_16x16x32_bf16(av, fr[SL], acc[TI], 0, 0, 0);

    const int B0 = 4095 - t0 - n + 8 * g;
    // prefill ALL slots with frag(ti, 0)
#pragma unroll
    for (int ti = 0; ti < 16; ++ti) LOADF(ti, B0 - 16 * ti)
    q0a = yq[2 * g];     q0b = yq[2 * g + 1];
    q1a = yq[8 + 2 * g]; q1b = yq[8 + 2 * g + 1];
    int bcur = B0;
    int yn = 16 + 2 * g;   // float4 index of y prefetch, 2 steps ahead

// One step: consume oldest slots first, reload them for next step, 14 more MFMAs.
// YI = y prefetch index expression (affine in main loop, clamped in tail).
#define STEPB(YI, S0,S1,S2,S3,S4,S5,S6,S7,S8,S9,S10,S11,S12,S13,S14,S15) { \
    PACKAV(q0a, q0b); \
    q0a = q1a; q0b = q1b; \
    __builtin_amdgcn_s_setprio(1); \
    MF(14, S14) MF(15, S15) \
    LOADF(S14, bcur + 32) LOADF(S15, bcur + 16) \
    q1a = yq[(YI)]; q1b = yq[(YI) + 1]; \
    yn += 8; bcur += 32; \
    MF(0,S0) MF(1,S1) MF(2,S2) MF(3,S3) MF(4,S4) MF(5,S5) MF(6,S6) MF(7,S7) \
    MF(8,S8) MF(9,S9) MF(10,S10) MF(11,S11) MF(12,S12) MF(13,S13) \
    __builtin_amdgcn_s_setprio(0); \
}

#define ROUND8(YIM) \
    STEPB(YIM, 0,1,2,3,4,5,6,7,8,9,10,11,12,13,14,15) \
    STEPB(YIM, 14,15,0,1,2,3,4,5,6,7,8,9,10,11,12,13) \
    STEPB(YIM, 12,13,14,15,0,1,2,3,4,5,6,7,8,9,10,11) \
    STEPB(YIM, 10,11,12,13,14,15,0,1,2,3,4,5,6,7,8,9) \
    STEPB(YIM, 8,9,10,11,12,13,14,15,0,1,2,3,4,5,6,7) \
    STEPB(YIM, 6,7,8,9,10,11,12,13,14,15,0,1,2,3,4,5) \
    STEPB(YIM, 4,5,6,7,8,9,10,11,12,13,14,15,0,1,2,3) \
    STEPB(YIM, 2,3,4,5,6,7,8,9,10,11,12,13,14,15,0,1)

    const int nfull = S >> 3;
    for (int it = 0; it < nfull - 1; ++it) {
        ROUND8(yn)
    }
    // final iteration: clamp y prefetch (last 2 steps of v=15 would run past row end)
    ROUND8(yn < 1016 ? yn : 1016)

#undef ROUND8
#undef STEPB
#undef MF
#undef PACKAV
#undef PK2
#undef LOADF

    // ---- epilogue: out = acc + D*y ----
    const float D0 = Dp[0];
#pragma unroll
    for (int ti = 0; ti < 16; ++ti) {
        int tcol = t0 + 16 * ti + n;
#pragma unroll
        for (int r = 0; r < 4; ++r) {
            int dr = d0w + 4 * g + r;
            size_t ix = (size_t)dr * L_ + tcol;
            out[ix] = acc[ti][r] + D0 * y[ix];
        }
    }
}

// ---------------- host ----------------

extern "C" void kernel_launch(void* const* d_in, const int* in_sizes, int n_in,
                              void* d_out, int out_size, void* d_ws, size_t ws_size,
                              hipStream_t stream) {
    const float* y  = (const float*)d_in[0];
    const float* A  = (const float*)d_in[1];
    const float* Bv = (const float*)d_in[2];
    const float* Cv = (const float*)d_in[3];
    const float* Dp = (const float*)d_in[4];
    float* out = (float*)d_out;
    float* w = (float*)d_ws;

    float* W   = w;                    // 64 x 256
    float* V   = w + 16384;            // 256 x 64
    float* Kf  = w + 32768;            // 4096
    uint2* Rqg = (uint2*)(w + 36864);  // 4608 quads

    k_kry<<<dim3(2), dim3(1024), 0, stream>>>(A, Bv, Cv, W, V);
    k_g<<<dim3(2, 2), dim3(256), 0, stream>>>(W, V, Kf, 64, 64, 256, 64, 64, 1.0f, 0.0f);
    k_pack<<<dim3(18), dim3(256), 0, stream>>>(Kf, Rqg);
    k_conv<<<dim3(32, 16), dim3(256), 0, stream>>>(Rqg, y, Dp, out);

    (void)in_sizes; (void)n_in; (void)out_size; (void)ws_size;
}

// Round 9
// 78.815 us; speedup vs baseline: 4.8637x; 1.0170x over previous
//
#include <hip/hip_runtime.h>

#define N_ 256
#define L_ 4096
#define DM_ 2048
#define STEPF (1.0f / 4096.0f)
#define NW 15   // W-side Taylor terms: ||0.984*A||~2 -> 2^15/15! ~ 2.5e-8 (K rel-err << bf16)
#define NV 6    // V-side Taylor terms
#define RQN 4608

typedef short bf16x8 __attribute__((ext_vector_type(8)));
typedef float f32x4 __attribute__((ext_vector_type(4)));
typedef unsigned int uint32;

__device__ __forceinline__ uint32 bf16rne(float f) {
    uint32 u = __builtin_bit_cast(uint32, f);
    return (u + 0x7FFFu + ((u >> 16) & 1u)) >> 16;
}
__device__ __forceinline__ float rdlane(float v, int l) {
    return __builtin_bit_cast(float, __builtin_amdgcn_readlane(__builtin_bit_cast(int, v), l));
}

// ---------------- Phase 1a: Krylov build of W (64x256) and V (256x64) ----------------
// S := ln(Abar) = step*A + O(M^3).  W[q,:] = C exp(64q S) = sum_n vt_n (q/63)^n,
// vt_n = C (4032 S)^n/n!.  V[:,r] = exp(r S) Bbar = sum_n ut_n (r/63)^n.
__global__ __launch_bounds__(1024) void k_kry(const float* __restrict__ Araw,
                                              const float* __restrict__ Bv,
                                              const float* __restrict__ Cv,
                                              float* __restrict__ W,
                                              float* __restrict__ V) {
    __shared__ float kry[NW][256];
    __shared__ float red[4][256];
    __shared__ float cur[256];
    const int tid = threadIdx.x;
    const int j = tid & 255, seg = tid >> 8, lane = tid & 63;

#define DOT64(S0, S1, VV) { \
    _Pragma("unroll") \
    for (int m = 0; m < 64; m += 2) { \
        S0 = fmaf(rdlane(VV, m), a[m], S0); \
        S1 = fmaf(rdlane(VV, m + 1), a[m + 1], S1); \
    } }

    if (blockIdx.x == 0) {
        float a[64];
#pragma unroll
        for (int m = 0; m < 64; ++m) a[m] = Araw[(64 * seg + m) * 256 + j];  // A[k][j]
        if (tid < 256) kry[0][tid] = Cv[tid];
        __syncthreads();
        const float WSC = 4032.0f / 4096.0f;
        for (int n = 1; n < NW; ++n) {
            float vv = kry[n - 1][64 * seg + lane];
            float s0 = 0.f, s1 = 0.f;
            DOT64(s0, s1, vv)
            red[seg][j] = s0 + s1;
            __syncthreads();
            if (tid < 256)
                kry[n][tid] = (red[0][tid] + red[1][tid] + red[2][tid] + red[3][tid]) * (WSC / (float)n);
            __syncthreads();
        }
        float kj[NW];
#pragma unroll
        for (int n = 0; n < NW; ++n) kj[n] = kry[n][j];
        for (int u = 0; u < 16; ++u) {
            int q = seg + 4 * u;
            float c = (float)q * (1.0f / 63.0f);
            float h = kj[NW - 1];
#pragma unroll
            for (int n = NW - 2; n >= 0; --n) h = fmaf(c, h, kj[n]);
            W[q * 256 + j] = h;
        }
    } else {
        float a[64];
#pragma unroll
        for (int m = 0; m < 64; ++m) a[m] = Araw[j * 256 + 64 * seg + m];  // A[i][k]
        if (tid < 256) cur[tid] = Bv[tid];
        __syncthreads();
        const float ms = 0.5f * STEPF;
        for (int it = 0; it < 3; ++it) {
            float vv = cur[64 * seg + lane];
            float s0 = 0.f, s1 = 0.f;
            DOT64(s0, s1, vv)
            red[seg][j] = s0 + s1;
            __syncthreads();
            if (tid < 256)
                cur[tid] = fmaf(ms, red[0][tid] + red[1][tid] + red[2][tid] + red[3][tid], Bv[tid]);
            __syncthreads();
        }
        if (tid < 256) kry[0][tid] = STEPF * cur[tid];
        __syncthreads();
        const float VSC = 63.0f / 4096.0f;
        for (int n = 1; n < NV; ++n) {
            float vv = kry[n - 1][64 * seg + lane];
            float s0 = 0.f, s1 = 0.f;
            DOT64(s0, s1, vv)
            red[seg][j] = s0 + s1;
            __syncthreads();
            if (tid < 256)
                kry[n][tid] = (red[0][tid] + red[1][tid] + red[2][tid] + red[3][tid]) * (VSC / (float)n);
            __syncthreads();
        }
        float kj[NV];
#pragma unroll
        for (int n = 0; n < NV; ++n) kj[n] = kry[n][j];
        for (int u = 0; u < 16; ++u) {
            int r = seg + 4 * u;
            float c = (float)r * (1.0f / 63.0f);
            float h = kj[NV - 1];
#pragma unroll
            for (int n = NV - 2; n >= 0; --n) h = fmaf(c, h, kj[n]);
            V[j * 64 + r] = h;
        }
    }
#undef DOT64
}

// ---------------- Phase 1b: small GEMM Kf = W * V  (Kf[64q + r] = K[l]) ----------------
__global__ __launch_bounds__(256) void k_g(const float* __restrict__ A, const float* __restrict__ B,
                                           float* __restrict__ C, int Ma, int Nb,
                                           int lda, int ldb, int ldc, float alpha, float diagv) {
    int row0 = blockIdx.y * 32, col0 = blockIdx.x * 32;
    if (row0 >= Ma || col0 >= Nb) return;
    __shared__ float As[16][33], Bs[16][33];
    int tid = threadIdx.x;
    int tx = tid & 15, ty = tid >> 4;
    int e0 = tid * 2, e1 = e0 + 1;
    int ai0 = e0 >> 4, ak0 = e0 & 15, ai1 = e1 >> 4, ak1 = e1 & 15;
    int bj0 = e0 & 31, bk0 = e0 >> 5, bj1 = e1 & 31, bk1 = e1 >> 5;
    bool va0 = (row0 + ai0) < Ma, va1 = (row0 + ai1) < Ma;
    bool vb0 = (col0 + bj0) < Nb, vb1 = (col0 + bj1) < Nb;
    float a0p = va0 ? A[(row0 + ai0) * lda + ak0] : 0.f;
    float a1p = va1 ? A[(row0 + ai1) * lda + ak1] : 0.f;
    float b0p = vb0 ? B[bk0 * ldb + col0 + bj0] : 0.f;
    float b1p = vb1 ? B[bk1 * ldb + col0 + bj1] : 0.f;
    float acc00 = 0.f, acc01 = 0.f, acc10 = 0.f, acc11 = 0.f;
    for (int kk = 0; kk < 256; kk += 16) {
        As[ak0][ai0] = a0p; As[ak1][ai1] = a1p;
        Bs[bk0][bj0] = b0p; Bs[bk1][bj1] = b1p;
        __syncthreads();
        if (kk + 16 < 256) {
            a0p = va0 ? A[(row0 + ai0) * lda + kk + 16 + ak0] : 0.f;
            a1p = va1 ? A[(row0 + ai1) * lda + kk + 16 + ak1] : 0.f;
            b0p = vb0 ? B[(bk0 + kk + 16) * ldb + col0 + bj0] : 0.f;
            b1p = vb1 ? B[(bk1 + kk + 16) * ldb + col0 + bj1] : 0.f;
        }
#pragma unroll
        for (int k = 0; k < 16; ++k) {
            float a0 = As[k][ty * 2], a1 = As[k][ty * 2 + 1];
            float b0 = Bs[k][tx * 2], b1 = Bs[k][tx * 2 + 1];
            acc00 = fmaf(a0, b0, acc00); acc01 = fmaf(a0, b1, acc01);
            acc10 = fmaf(a1, b0, acc10); acc11 = fmaf(a1, b1, acc11);
        }
        __syncthreads();
    }
    float accs[2][2] = {{acc00, acc01}, {acc10, acc11}};
#pragma unroll
    for (int i = 0; i < 2; ++i) {
        int r = row0 + ty * 2 + i;
        if (r < Ma)
#pragma unroll
            for (int jj = 0; jj < 2; ++jj) {
                int c = col0 + tx * 2 + jj;
                if (c < Nb) {
                    float v = alpha * accs[i][jj];
                    if (r == c) v += diagv;
                    C[r * ldc + c] = v;
                }
            }
    }
}

// ---------------- Phase 1c: pack reversed-K quad table to global ----------------
// Rqg[i] = rev[i..i+3] as 4 bf16 (uint2), rev[x] = K[4095-x], 0 when OOB.
__global__ __launch_bounds__(256) void k_pack(const float* __restrict__ Kf, uint2* __restrict__ Rqg) {
    int i = blockIdx.x * 256 + threadIdx.x;   // grid 18*256 = 4608
    int a = 4095 - i;
    uint32 e0 = (a >= 0) ? bf16rne(Kf[a]) : 0u;
    uint32 e1 = (a >= 1) ? bf16rne(Kf[a - 1]) : 0u;
    uint32 e2 = (a >= 2) ? bf16rne(Kf[a - 2]) : 0u;
    uint32 e3 = (a >= 3) ? bf16rne(Kf[a - 3]) : 0u;
    uint2 v; v.x = e0 | (e1 << 16); v.y = e2 | (e3 << 16);
    Rqg[i] = v;
}

// ---------------- Phase 2: MFMA causal conv, T=16, balanced t-pairing ----------------
// Out[d,t] = sum_j y[d,j] K[t-j].  4 waves = 4 d-subtiles (64 d-rows) per block.
// Each wave runs TWO t-strips: v = 15-by then v = by -> total steps
// 8(16-by)+8(by+1) = 136 for EVERY wave. Grid (32,8) = 256 blocks = 1/CU, all
// resident start-to-finish, zero drain. Step body identical to R8 (proven).
__global__ __launch_bounds__(256, 2) void k_conv(const uint2* __restrict__ Rqg,
                                                 const float* __restrict__ y,
                                                 const float* __restrict__ Dp,
                                                 float* __restrict__ out) {
    __shared__ uint2 Rq[RQN];
    const int tid = threadIdx.x;
#pragma unroll
    for (int i = 0; i < RQN / 256; ++i) Rq[i * 256 + tid] = Rqg[i * 256 + tid];
    __syncthreads();

    const int w = tid >> 6, lane = tid & 63;
    const int n = lane & 15, g = lane >> 4;
    const int by = (int)blockIdx.y;                   // 0..7
    const int d0w = (int)blockIdx.x * 64 + w * 16;
    const int d = d0w + n;
    const float4* __restrict__ yq = (const float4*)(y + (size_t)d * L_);
    const float D0 = Dp[0];

#define LOADF(SL, I0) { \
    uint2 u0 = Rq[(I0)]; uint2 u1 = Rq[(I0) + 4]; \
    uint4 uu; uu.x = u0.x; uu.y = u0.y; uu.z = u1.x; uu.w = u1.y; \
    fr[SL] = __builtin_bit_cast(bf16x8, uu); }
// pk2 as one v_perm: result bytes = {hi.b3, hi.b2, lo.b3, lo.b2} (bf16 truncation)
#define PK2(LO, HI) __builtin_amdgcn_perm(__builtin_bit_cast(uint32, (HI)), \
                                          __builtin_bit_cast(uint32, (LO)), 0x07060302u)
#define PACKAV(Q0, Q1) { \
    uint4 ua; ua.x = PK2((Q0).x, (Q0).y); ua.y = PK2((Q0).z, (Q0).w); \
    ua.z = PK2((Q1).x, (Q1).y); ua.w = PK2((Q1).z, (Q1).w); \
    av = __builtin_bit_cast(bf16x8, ua); }
#define MF(TI, SL) acc[TI] = __builtin_amdgcn_mfma_f32_16x16x32_bf16(av, fr[SL], acc[TI], 0, 0, 0);

#define STEPB(YI, S0,S1,S2,S3,S4,S5,S6,S7,S8,S9,S10,S11,S12,S13,S14,S15) { \
    PACKAV(q0a, q0b); \
    q0a = q1a; q0b = q1b; \
    __builtin_amdgcn_s_setprio(1); \
    MF(14, S14) MF(15, S15) \
    LOADF(S14, bcur + 32) LOADF(S15, bcur + 16) \
    q1a = yq[(YI)]; q1b = yq[(YI) + 1]; \
    yn += 8; bcur += 32; \
    MF(0,S0) MF(1,S1) MF(2,S2) MF(3,S3) MF(4,S4) MF(5,S5) MF(6,S6) MF(7,S7) \
    MF(8,S8) MF(9,S9) MF(10,S10) MF(11,S11) MF(12,S12) MF(13,S13) \
    __builtin_amdgcn_s_setprio(0); \
}

#define ROUND8(YIM) \
    STEPB(YIM, 0,1,2,3,4,5,6,7,8,9,10,11,12,13,14,15) \
    STEPB(YIM, 14,15,0,1,2,3,4,5,6,7,8,9,10,11,12,13) \
    STEPB(YIM, 12,13,14,15,0,1,2,3,4,5,6,7,8,9,10,11) \
    STEPB(YIM, 10,11,12,13,14,15,0,1,2,3,4,5,6,7,8,9) \
    STEPB(YIM, 8,9,10,11,12,13,14,15,0,1,2,3,4,5,6,7) \
    STEPB(YIM, 6,7,8,9,10,11,12,13,14,15,0,1,2,3,4,5) \
    STEPB(YIM, 4,5,6,7,8,9,10,11,12,13,14,15,0,1,2,3) \
    STEPB(YIM, 2,3,4,5,6,7,8,9,10,11,12,13,14,15,0,1)

    for (int strip = 0; strip < 2; ++strip) {
        const int v = strip ? by : (15 - by);
        const int t0 = v << 8;
        const int S = 8 * (v + 1);                    // j-steps (chunks of 32)

        f32x4 acc[16];
#pragma unroll
        for (int i = 0; i < 16; ++i) acc[i] = (f32x4){0.f, 0.f, 0.f, 0.f};
        bf16x8 fr[16], av;
        float4 q0a, q0b, q1a, q1b;

        const int B0 = 4095 - t0 - n + 8 * g;
#pragma unroll
        for (int ti = 0; ti < 16; ++ti) LOADF(ti, B0 - 16 * ti)
        q0a = yq[2 * g];     q0b = yq[2 * g + 1];
        q1a = yq[8 + 2 * g]; q1b = yq[8 + 2 * g + 1];
        int bcur = B0;
        int yn = 16 + 2 * g;   // float4 index of y prefetch, 2 steps ahead

        const int nfull = S >> 3;
        for (int it = 0; it < nfull - 1; ++it) {
            ROUND8(yn)
        }
        // final round: clamp y prefetch (only the v=15 strip can run past row end)
        ROUND8(yn < 1016 ? yn : 1016)

        // ---- epilogue: out = acc + D*y for this strip ----
#pragma unroll
        for (int ti = 0; ti < 16; ++ti) {
            int tcol = t0 + 16 * ti + n;
#pragma unroll
            for (int r = 0; r < 4; ++r) {
                int dr = d0w + 4 * g + r;
                size_t ix = (size_t)dr * L_ + tcol;
                out[ix] = acc[ti][r] + D0 * y[ix];
            }
        }
    }

#undef ROUND8
#undef STEPB
#undef MF
#undef PACKAV
#undef PK2
#undef LOADF
}

// ---------------- host ----------------

extern "C" void kernel_launch(void* const* d_in, const int* in_sizes, int n_in,
                              void* d_out, int out_size, void* d_ws, size_t ws_size,
                              hipStream_t stream) {
    const float* y  = (const float*)d_in[0];
    const float* A  = (const float*)d_in[1];
    const float* Bv = (const float*)d_in[2];
    const float* Cv = (const float*)d_in[3];
    const float* Dp = (const float*)d_in[4];
    float* out = (float*)d_out;
    float* w = (float*)d_ws;

    float* W   = w;                    // 64 x 256
    float* V   = w + 16384;            // 256 x 64
    float* Kf  = w + 32768;            // 4096
    uint2* Rqg = (uint2*)(w + 36864);  // 4608 quads

    k_kry<<<dim3(2), dim3(1024), 0, stream>>>(A, Bv, Cv, W, V);
    k_g<<<dim3(2, 2), dim3(256), 0, stream>>>(W, V, Kf, 64, 64, 256, 64, 64, 1.0f, 0.0f);
    k_pack<<<dim3(18), dim3(256), 0, stream>>>(Kf, Rqg);
    k_conv<<<dim3(32, 8), dim3(256), 0, stream>>>(Rqg, y, Dp, out);

    (void)in_sizes; (void)n_in; (void)out_size; (void)ws_size;
}